// Round 11
// baseline (671.791 us; speedup 1.0000x reference)
//
#include <hip/hip_runtime.h>

typedef unsigned short ushort_t;  // raw bf16 bits
typedef __attribute__((ext_vector_type(4))) float f32x4;
typedef __attribute__((ext_vector_type(8))) short s16x8;
typedef __attribute__((ext_vector_type(4))) short s16x4;

#define MFMA16(a, b, c) __builtin_amdgcn_mfma_f32_16x16x32_bf16((a), (b), (c), 0, 0, 0)

__device__ __forceinline__ float us2f(unsigned short u) {
  union { unsigned int i; float f; } v; v.i = ((unsigned int)u) << 16; return v.f;
}
__device__ __forceinline__ unsigned short f2us(float f) {
  union { float f; unsigned int i; } v; v.f = f;
  unsigned int x = v.i;
  return (unsigned short)((x + 0x7FFFu + ((x >> 16) & 1u)) >> 16);
}
__device__ __forceinline__ s16x8 ld8f(const float* p) {
  f32x4 a = *reinterpret_cast<const f32x4*>(p);
  f32x4 b = *reinterpret_cast<const f32x4*>(p + 4);
  s16x8 r;
  r[0] = (short)f2us(a[0]); r[1] = (short)f2us(a[1]);
  r[2] = (short)f2us(a[2]); r[3] = (short)f2us(a[3]);
  r[4] = (short)f2us(b[0]); r[5] = (short)f2us(b[1]);
  r[6] = (short)f2us(b[2]); r[7] = (short)f2us(b[3]);
  return r;
}
__device__ __forceinline__ float sigm(float x) { return 1.0f / (1.0f + __expf(-x)); }
__device__ __forceinline__ float tanh_f(float x) {
  float e = __expf(-2.0f * fabsf(x));
  float t = (1.0f - e) / (1.0f + e);
  return x < 0.0f ? -t : t;
}
// fast variants for the GRU hot loop (rcp-based, no div refinement)
__device__ __forceinline__ float fast_sigm(float x) {
  return __builtin_amdgcn_rcpf(1.0f + __expf(-x));
}
__device__ __forceinline__ float fast_tanh(float y) {
  float yc = fminf(fmaxf(y, -15.0f), 15.0f);
  float e2 = __expf(2.0f * yc);
  return (e2 - 1.0f) * __builtin_amdgcn_rcpf(e2 + 1.0f);
}

// ---------------------------------------------------------------------------
// f32 -> bf16 weight preconversion into ws:
// [0,196608) whh_q | [196608,393216) whh_p | [393216,425984) q_fc1_w |
// [425984,622592) q_attn_in_w
// ---------------------------------------------------------------------------
__global__ __launch_bounds__(256) void conv_k(
    const float* __restrict__ s0, const float* __restrict__ s1,
    const float* __restrict__ s2, const float* __restrict__ s3,
    ushort_t* __restrict__ d) {
  int i = blockIdx.x * 256 + threadIdx.x;
  if (i >= 155648) return;
  long e = (long)i * 4;
  const float* s; long off;
  if (e < 196608) { s = s0; off = e; }
  else if (e < 393216) { s = s1; off = e - 196608; }
  else if (e < 425984) { s = s2; off = e - 393216; }
  else { s = s3; off = e - 425984; }
  f32x4 v = *reinterpret_cast<const f32x4*>(s + off);
  s16x4 r;
  r[0] = (short)f2us(v[0]); r[1] = (short)f2us(v[1]);
  r[2] = (short)f2us(v[2]); r[3] = (short)f2us(v[3]);
  *reinterpret_cast<s16x4*>(d + e) = r;
}

// ---------------------------------------------------------------------------
// Grid GEMM (round-8 structure, NF<=4): out = epi(A[M,K] @ W[N,K]^T + bias)
// grid = (M/128, N/BN, [1|2]). z-batch via (A2,W2,bias2,out2).
// QKV epilogue: col<256 -> q rows (e<8) *0.125 -> qout; col>=256 -> kv.
// ---------------------------------------------------------------------------
template <int BN, int EPI, int ROWSEL, int RELU, int AF32, int WF32, int OF32,
          int QKV, int HB>
__global__ __launch_bounds__(256) void gemm_k(
    const void* __restrict__ A_, const void* __restrict__ W_,
    const float* __restrict__ bias, const int* __restrict__ em,
    void* __restrict__ out_, ushort_t* __restrict__ qout, long row0,
    int M, int N, int K,
    const void* __restrict__ A2_, const void* __restrict__ W2_,
    const float* __restrict__ bias2, void* __restrict__ out2_) {
  constexpr int NF = BN / 32;
  if (A2_ != nullptr && blockIdx.z != 0) {
    A_ = A2_; W_ = W2_; bias = bias2; out_ = out2_;
  }
  const float* Af = (const float*)A_;
  const ushort_t* Ab = (const ushort_t*)A_;
  const float* Wf = (const float*)W_;
  const ushort_t* Wb = (const ushort_t*)W_;
  float* outf = (float*)out_;
  ushort_t* outb = (ushort_t*)out_;
  __shared__ ushort_t As[128 * 40];
  __shared__ ushort_t Ws[BN * 40];
  const int tid = threadIdx.x;
  const int lane = tid & 63;
  const int wid = tid >> 6;
  const int wm = wid & 1, wn = wid >> 1;
  const int m0 = blockIdx.x * 128;
  const int n0 = blockIdx.y * BN;
  const int fr = lane & 15;
  const int kb = (lane >> 4) * 8;
  const int rb = (lane >> 4) * 4;

  f32x4 acc[4][NF];
#pragma unroll
  for (int i = 0; i < 4; i++)
#pragma unroll
    for (int j = 0; j < NF; j++) acc[i][j] = (f32x4){0.f, 0.f, 0.f, 0.f};

  for (int k0 = 0; k0 < K; k0 += 32) {
    __syncthreads();
    for (int c = tid; c < 512; c += 256) {
      int row = c >> 2, kc = (c & 3) * 8;
      int gr = m0 + row;
      long ar = ROWSEL ? ((long)(gr >> 3) * 64 + (gr & 7)) : (long)gr;
      s16x8 vv;
      if (AF32) vv = ld8f(&Af[ar * (long)K + k0 + kc]);
      else vv = *reinterpret_cast<const s16x8*>(&Ab[ar * (long)K + k0 + kc]);
      *reinterpret_cast<s16x8*>(&As[row * 40 + kc]) = vv;
    }
    for (int c = tid; c < BN * 4; c += 256) {
      int row = c >> 2, kc = (c & 3) * 8;
      s16x8 wv;
      if (WF32) wv = ld8f(&Wf[(long)(n0 + row) * K + k0 + kc]);
      else wv = *reinterpret_cast<const s16x8*>(&Wb[(long)(n0 + row) * K + k0 + kc]);
      *reinterpret_cast<s16x8*>(&Ws[row * 40 + kc]) = wv;
    }
    __syncthreads();
    s16x8 af[4], wf[NF];
#pragma unroll
    for (int mi = 0; mi < 4; mi++)
      af[mi] = *reinterpret_cast<const s16x8*>(&As[(wm * 64 + mi * 16 + fr) * 40 + kb]);
#pragma unroll
    for (int ni = 0; ni < NF; ni++)
      wf[ni] = *reinterpret_cast<const s16x8*>(&Ws[(wn * (BN / 2) + ni * 16 + fr) * 40 + kb]);
#pragma unroll
    for (int mi = 0; mi < 4; mi++)
#pragma unroll
      for (int ni = 0; ni < NF; ni++) acc[mi][ni] = MFMA16(af[mi], wf[ni], acc[mi][ni]);
  }

#pragma unroll
  for (int ni = 0; ni < NF; ni++) {
    int col = n0 + wn * (BN / 2) + ni * 16 + fr;
    float bv = HB ? bias[col] : 0.0f;
#pragma unroll
    for (int mi = 0; mi < 4; mi++) {
#pragma unroll
      for (int rr = 0; rr < 4; rr++) {
        int row = m0 + wm * 64 + mi * 16 + rb + rr;
        float v = acc[mi][ni][rr] + bv;
        if (RELU) v = fmaxf(v, 0.0f);
        if (EPI == 2 || EPI == 3) {
          if (em[(long)(row >> 3) * 64 + (row & 7)] != 0) v = (EPI == 2) ? 0.0f : -1.0e10f;
        }
        if (QKV) {
          long grow = row0 + row;
          int e = (int)(grow & 63);
          if (col < 256) {
            if (e < 8) qout[((grow >> 6) * 8 + e) * 256 + col] = f2us(v * 0.125f);
          } else {
            outb[(long)row * 512 + (col - 256)] = f2us(v);
          }
        } else if (OF32) {
          outf[(long)row * N + col] = v;
        } else {
          outb[(long)row * N + col] = f2us(v);
        }
      }
    }
  }
}

// ---------------------------------------------------------------------------
// Attention core (unchanged, passing): one block per batch.
// ---------------------------------------------------------------------------
__global__ __launch_bounds__(512) void attn2_k(
    const ushort_t* __restrict__ kv, const ushort_t* __restrict__ qbuf,
    const int* __restrict__ obs, ushort_t* __restrict__ attn_out, int b0) {
  __shared__ ushort_t qs[16 * 264];
  __shared__ ushort_t ks[64 * 264];
  __shared__ ushort_t vs[64 * 264];
  __shared__ float lg[32 * 66];
  __shared__ int oms[512];

  const int b_loc = blockIdx.x;
  const long b = b0 + b_loc;
  const int tid = threadIdx.x;
  const int lane = tid & 63;
  const int w = tid >> 6;
  const int fr = lane & 15, kb = (lane >> 4) * 8, rb = (lane >> 4) * 4;

  oms[tid] = obs[b * 4096 + tid];
  {
    int row = tid >> 5, cc = (tid & 31) * 8;
    if (tid < 256) {
      *reinterpret_cast<s16x8*>(&qs[row * 264 + cc]) =
          *reinterpret_cast<const s16x8*>(&qbuf[(b * 8 + row) * 256 + cc]);
    } else {
      *reinterpret_cast<s16x8*>(&qs[row * 264 + cc]) = (s16x8){0,0,0,0,0,0,0,0};
    }
  }
  for (int i = 0; i < 4; i++) {
    int e = i * 16 + (tid >> 5);
    int cc = (tid & 31) * 8;
    const ushort_t* src = &kv[((long)(b_loc * 64 + e)) * 512];
    *reinterpret_cast<s16x8*>(&ks[e * 264 + cc]) =
        *reinterpret_cast<const s16x8*>(&src[cc]);
    *reinterpret_cast<s16x8*>(&vs[e * 264 + cc]) =
        *reinterpret_cast<const s16x8*>(&src[256 + cc]);
  }
  __syncthreads();

  {
    const int h = w >> 1, np = w & 1;
    f32x4 lacc[2];
    lacc[0] = (f32x4){0.f, 0.f, 0.f, 0.f};
    lacc[1] = (f32x4){0.f, 0.f, 0.f, 0.f};
#pragma unroll
    for (int k0 = 0; k0 < 64; k0 += 32) {
      s16x8 af = *reinterpret_cast<const s16x8*>(&qs[fr * 264 + h * 64 + k0 + kb]);
#pragma unroll
      for (int j = 0; j < 2; j++) {
        int e0 = (np * 2 + j) * 16;
        s16x8 bf = *reinterpret_cast<const s16x8*>(&ks[(e0 + fr) * 264 + h * 64 + k0 + kb]);
        lacc[j] = MFMA16(af, bf, lacc[j]);
      }
    }
#pragma unroll
    for (int j = 0; j < 2; j++) {
      int e = (np * 2 + j) * 16 + fr;
#pragma unroll
      for (int rr = 0; rr < 4; rr++) {
        int a = rb + rr;
        if (a < 8)
          lg[(a * 4 + h) * 66 + e] = (oms[a * 64 + e] != 0) ? -1.0e30f : lacc[j][rr];
      }
    }
  }
  __syncthreads();

  {
    int ri = tid >> 4, sub = tid & 15;
    float v4[4];
#pragma unroll
    for (int j = 0; j < 4; j++) v4[j] = lg[ri * 66 + sub * 4 + j];
    float m = fmaxf(fmaxf(v4[0], v4[1]), fmaxf(v4[2], v4[3]));
#pragma unroll
    for (int d = 1; d < 16; d <<= 1) m = fmaxf(m, __shfl_xor(m, d));
    bool dead = (m < -5.0e29f);
    float s = 0.0f;
#pragma unroll
    for (int j = 0; j < 4; j++) { v4[j] = __expf(v4[j] - m); s += v4[j]; }
#pragma unroll
    for (int d = 1; d < 16; d <<= 1) s += __shfl_xor(s, d);
    float inv = dead ? 0.0f : (1.0f / s);
#pragma unroll
    for (int j = 0; j < 4; j++) lg[ri * 66 + sub * 4 + j] = v4[j] * inv;
  }
  __syncthreads();

  {
    int a = tid >> 6, d0 = (tid & 63) * 4, h = d0 >> 6;
    const float* wrow = &lg[(a * 4 + h) * 66];
    float facc[4] = {0.f, 0.f, 0.f, 0.f};
    for (int e = 0; e < 64; e++) {
      float wv = wrow[e];
      s16x4 vv = *reinterpret_cast<const s16x4*>(&vs[e * 264 + d0]);
#pragma unroll
      for (int j = 0; j < 4; j++) facc[j] += wv * us2f((unsigned short)vv[j]);
    }
    s16x4 r;
#pragma unroll
    for (int j = 0; j < 4; j++) r[j] = (short)f2us(facc[j]);
    *reinterpret_cast<s16x4*>(&attn_out[(b * 8 + a) * 256 + d0]) = r;
  }
}

// ---------------------------------------------------------------------------
// GRU scan v5: gru4 structure + VALU diet:
// - bhh folded into MFMA C-init (acc starts at bias)
// - v_cvt_pk_bf16_f32 for h staging (2 f32 -> 2 bf16 per inst)
// - rcp-based sigmoid / clamped-exp tanh (no div refinement, no sign select)
// - hn = n + z*(h-n)
// - s_setprio(1) around the MFMA cluster (waves are phase-split)
// ---------------------------------------------------------------------------
__global__ __launch_bounds__(1024, 4) void gru5_k(
    const ushort_t* __restrict__ gi_q, const ushort_t* __restrict__ gi_p,
    const ushort_t* __restrict__ whhb_q, const ushort_t* __restrict__ whhb_p,
    const float* __restrict__ bhh_q, const float* __restrict__ bhh_p,
    const float* __restrict__ h0_q, const float* __restrict__ h0_p,
    float* __restrict__ hs_q, float* __restrict__ hs_p) {
  __shared__ ushort_t nw[256 * 256];     // n-gate weights, swizzled, 128KB
  __shared__ ushort_t hls[2][16 * 264];  // double-buffered h staging
  const int bid = blockIdx.x;
  const int mdl = bid >> 4, cg = bid & 15;
  const ushort_t* gi = mdl ? gi_p : gi_q;
  const ushort_t* whh = mdl ? whhb_p : whhb_q;
  const float* bhh = mdl ? bhh_p : bhh_q;
  const float* h0 = mdl ? h0_p : h0_q;
  float* hs = mdl ? hs_p : hs_q;

  const int tid = threadIdx.x;
  const int lane = tid & 63, w = tid >> 6;
  const int fr = lane & 15, kb = (lane >> 4) * 8, rb = (lane >> 4) * 4;
  const int col = w * 16 + fr;

  s16x8 wrz[2][8];
#pragma unroll
  for (int g = 0; g < 2; g++)
#pragma unroll
    for (int ks = 0; ks < 8; ks++)
      wrz[g][ks] = *reinterpret_cast<const s16x8*>(
          &whh[(g * 256 + col) * 256 + ks * 32 + kb]);

  char* nwb = (char*)nw;
  for (int c = tid; c < 8192; c += 1024) {
    int row = c >> 5, kc = (c & 31) * 8;
    *reinterpret_cast<s16x8*>(nwb + row * 512 + ((kc * 2) ^ ((row & 7) << 4))) =
        *reinterpret_cast<const s16x8*>(&whh[(512 + row) * 256 + kc]);
  }

  int nwaddr[8];
#pragma unroll
  for (int ks = 0; ks < 8; ks++)
    nwaddr[ks] = col * 512 + (((ks * 32 + kb) * 2) ^ ((col & 7) << 4));

  float h[4], bh[3];
#pragma unroll
  for (int rr = 0; rr < 4; rr++) h[rr] = h0[(cg * 16 + rb + rr) * 256 + col];
#pragma unroll
  for (int g = 0; g < 3; g++) bh[g] = bhh[g * 256 + col];

  const int chain0 = cg * 16 + rb;
  const long r0 = (long)(chain0 >> 3) * 512 + (chain0 & 7);
  const ushort_t* gp0 = gi + r0 * 768 + col;
  float* hp0 = hs + r0 * 256 + col;
  ushort_t* hrow0 = &hls[0][rb * 264 + col];
  ushort_t* hrow1 = &hls[1][rb * 264 + col];

#define GRU_STEP(HROW, BUF)                                                    \
  {                                                                            \
    float gv[3][4];                                                            \
    _Pragma("unroll") for (int rr = 0; rr < 4; rr++) {                         \
      gv[0][rr] = us2f(gp0[rr * 768]);                                         \
      gv[1][rr] = us2f(gp0[rr * 768 + 256]);                                   \
      gv[2][rr] = us2f(gp0[rr * 768 + 512]);                                   \
    }                                                                          \
    gp0 += 6144;                                                               \
    unsigned int pk01, pk23;                                                   \
    asm("v_cvt_pk_bf16_f32 %0, %1, %2" : "=v"(pk01) : "v"(h[0]), "v"(h[1]));   \
    asm("v_cvt_pk_bf16_f32 %0, %1, %2" : "=v"(pk23) : "v"(h[2]), "v"(h[3]));   \
    HROW[0] = (ushort_t)(pk01 & 0xffffu);                                      \
    HROW[264] = (ushort_t)(pk01 >> 16);                                        \
    HROW[528] = (ushort_t)(pk23 & 0xffffu);                                    \
    HROW[792] = (ushort_t)(pk23 >> 16);                                        \
    __syncthreads();                                                           \
    f32x4 acc[3];                                                              \
    _Pragma("unroll") for (int i = 0; i < 3; i++)                              \
        acc[i] = (f32x4){bh[i], bh[i], bh[i], bh[i]};                          \
    __builtin_amdgcn_s_setprio(1);                                             \
    _Pragma("unroll") for (int ks = 0; ks < 8; ks++) {                         \
      s16x8 a = *reinterpret_cast<const s16x8*>(                               \
          &hls[BUF][fr * 264 + ks * 32 + kb]);                                 \
      acc[0] = MFMA16(a, wrz[0][ks], acc[0]);                                  \
      acc[1] = MFMA16(a, wrz[1][ks], acc[1]);                                  \
      s16x8 bn = *reinterpret_cast<const s16x8*>(nwb + nwaddr[ks]);            \
      acc[2] = MFMA16(a, bn, acc[2]);                                          \
    }                                                                          \
    __builtin_amdgcn_s_setprio(0);                                             \
    _Pragma("unroll") for (int rr = 0; rr < 4; rr++) {                         \
      float r_ = fast_sigm(gv[0][rr] + acc[0][rr]);                            \
      float z_ = fast_sigm(gv[1][rr] + acc[1][rr]);                            \
      float n_ = fast_tanh(gv[2][rr] + r_ * acc[2][rr]);                       \
      float hn = n_ + z_ * (h[rr] - n_);                                       \
      h[rr] = hn;                                                              \
      hp0[rr * 256] = hn;                                                      \
    }                                                                          \
    hp0 += 2048;                                                               \
  }

  for (int t2 = 0; t2 < 32; t2++) {
    GRU_STEP(hrow0, 0)
    GRU_STEP(hrow1, 1)
  }
#undef GRU_STEP
}

// ---------------------------------------------------------------------------
extern "C" void kernel_launch(void* const* d_in, const int* in_sizes, int n_in,
                              void* d_out, int out_size, void* d_ws, size_t ws_size,
                              hipStream_t stream) {
  (void)in_sizes; (void)n_in; (void)out_size; (void)ws_size;

  const float* entities = (const float*)d_in[0];
  const int* obs = (const int*)d_in[1];
  const int* em = (const int*)d_in[2];
  const float* hidq = (const float*)d_in[3];
  const float* hidp = (const float*)d_in[4];
  const float* q_fc1_w = (const float*)d_in[5];
  const float* q_fc1_b = (const float*)d_in[6];
  const float* q_fc2_w = (const float*)d_in[7];
  const float* q_fc2_b = (const float*)d_in[8];
  const float* q_wih = (const float*)d_in[9];
  const float* q_whh = (const float*)d_in[10];
  const float* q_bih = (const float*)d_in[11];
  const float* q_bhh = (const float*)d_in[12];
  const float* q_fcq_w = (const float*)d_in[13];
  const float* q_fcq_b = (const float*)d_in[14];
  const float* q_fcpi_w = (const float*)d_in[15];
  const float* q_fcpi_b = (const float*)d_in[16];
  const float* p_fc1_w = (const float*)d_in[17];
  const float* p_fc1_b = (const float*)d_in[18];
  const float* p_fc2_w = (const float*)d_in[19];
  const float* p_fc2_b = (const float*)d_in[20];
  const float* p_wih = (const float*)d_in[21];
  const float* p_whh = (const float*)d_in[22];
  const float* p_bih = (const float*)d_in[23];
  const float* p_bhh = (const float*)d_in[24];
  const float* p_fcpi_w = (const float*)d_in[27];
  const float* p_fcpi_b = (const float*)d_in[28];
  const float* inw = (const float*)d_in[29];
  const float* outw = (const float*)d_in[30];
  const float* outb = (const float*)d_in[31];

  // ws layout (bf16 elems). Peak 92.9M elems = 186 MB < proven 209 MB.
  // gi buffers overlay x1all (dead after the last kvq).
  ushort_t* ws = (ushort_t*)d_ws;
  ushort_t* qbuf  = ws;                  // [0, 4.19M)
  ushort_t* attn  = ws + 4194304l;       // [4.19M, 8.39M)
  ushort_t* x1all = ws + 8388608l;       // [8.39M, 41.94M)  33.55M elems
  ushort_t* giq   = ws + 8388608l;       //   overlay: 12.58M
  ushort_t* gip   = ws + 20971520l;      //   overlay: 12.58M
  ushort_t* kvc   = ws + 41943040l;      // [41.94M, 75.50M) 33.55M elems
  ushort_t* wcv   = ws + 75497472l;      // converted weights (622,592)
  ushort_t* wbq = wcv;
  ushort_t* wbp = wcv + 196608l;
  ushort_t* wf1 = wcv + 393216l;
  ushort_t* win = wcv + 425984l;
  ushort_t* x2b = ws + 76120064l;
  ushort_t* x3q = ws + 80314368l;
  ushort_t* x1p = ws + 84508672l;
  ushort_t* x3p = ws + 88702976l;        // end 92,897,280

  float* out = (float*)d_out;
  float* o_q = out;
  float* o_pi = out + 1048576l;
  float* o_piA = out + 2097152l;
  float* o_hq = out + 3145728l;
  float* o_hp = out + 7340032l;

  const int nc = 2, CB = 1024;
  const long MR = (long)CB * 64;  // 65536 rows per chunk
  const void* NUL = nullptr;

  // 0) pre-convert hot weights to bf16
  conv_k<<<608, 256, 0, stream>>>(q_whh, p_whh, q_fc1_w, inw, wcv);

  // 1) x1 = relu(ent @ fc1^T + b) — single dispatch, output L3-resident
  gemm_k<128, 0, 0, 1, 1, 0, 0, 0, 1><<<dim3(1024, 2), 256, 0, stream>>>(
      entities, wf1, q_fc1_b, em, x1all, nullptr, 0, 131072, 256, 128,
      NUL, NUL, nullptr, nullptr);
  // 2) kvq + attention, 2 chunks so kv stays L3-resident
  for (int c = 0; c < nc; c++) {
    gemm_k<128, 0, 0, 0, 0, 0, 0, 1, 0><<<dim3(512, 6), 256, 0, stream>>>(
        x1all + (long)c * MR * 256, win, nullptr, em, kvc, qbuf, (long)c * MR,
        (int)MR, 768, 256, NUL, NUL, nullptr, nullptr);
    attn2_k<<<CB, 512, 0, stream>>>(kvc, qbuf, obs, attn, c * CB);
  }
  // 3) x2 = mask0(attn @ outw^T + outb)
  gemm_k<128, 2, 0, 0, 0, 1, 0, 0, 1><<<dim3(128, 2), 256, 0, stream>>>(
      attn, outw, outb, em, x2b, nullptr, 0, 16384, 256, 256,
      NUL, NUL, nullptr, nullptr);
  // 4) x1p = relu(ent[:, :8] @ fc1^T + b)
  gemm_k<128, 0, 1, 1, 1, 1, 0, 0, 1><<<dim3(128, 2), 256, 0, stream>>>(
      entities, p_fc1_w, p_fc1_b, em, x1p, nullptr, 0, 16384, 256, 128,
      NUL, NUL, nullptr, nullptr);
  // 5) z-batched x3: {x3q = relu(x2@q_fc2)} | {x3p = relu(x1p@p_fc2)}
  gemm_k<128, 0, 0, 1, 0, 1, 0, 0, 1><<<dim3(128, 2, 2), 256, 0, stream>>>(
      x2b, q_fc2_w, q_fc2_b, em, x3q, nullptr, 0, 16384, 256, 256,
      x1p, p_fc2_w, p_fc2_b, x3p);
  // 6) z-batched gi: {giq = x3q@q_wih + bih} | {gip = x3p@p_wih + bih}
  //    (writes overlay x1all, which is dead after step 2)
  gemm_k<128, 0, 0, 0, 0, 1, 0, 0, 1><<<dim3(128, 6, 2), 256, 0, stream>>>(
      x3q, q_wih, q_bih, em, giq, nullptr, 0, 16384, 768, 256,
      x3p, p_wih, p_bih, gip);
  // 7) GRU scan v5
  gru5_k<<<32, 1024, 0, stream>>>(giq, gip, wbq, wbp, q_bhh, p_bhh, hidq, hidp,
                                  o_hq, o_hp);
  // 8) heads: o_q, then z-batched {pi from h_q} | {pi_avg from h_pi}
  gemm_k<64, 2, 0, 0, 1, 1, 1, 0, 1><<<dim3(128, 1), 256, 0, stream>>>(
      o_hq, q_fcq_w, q_fcq_b, em, o_q, nullptr, 0, 16384, 64, 256,
      NUL, NUL, nullptr, nullptr);
  gemm_k<64, 3, 0, 0, 1, 1, 1, 0, 1><<<dim3(128, 1, 2), 256, 0, stream>>>(
      o_hq, q_fcpi_w, q_fcpi_b, em, o_pi, nullptr, 0, 16384, 64, 256,
      o_hp, p_fcpi_b ? p_fcpi_w : p_fcpi_w, p_fcpi_b, o_piA);
}

// Round 12
// 649.629 us; speedup vs baseline: 1.0341x; 1.0341x over previous
//
#include <hip/hip_runtime.h>

typedef unsigned short ushort_t;  // raw bf16 bits
typedef __attribute__((ext_vector_type(4))) float f32x4;
typedef __attribute__((ext_vector_type(8))) short s16x8;
typedef __attribute__((ext_vector_type(4))) short s16x4;

#define MFMA16(a, b, c) __builtin_amdgcn_mfma_f32_16x16x32_bf16((a), (b), (c), 0, 0, 0)

__device__ __forceinline__ float us2f(unsigned short u) {
  union { unsigned int i; float f; } v; v.i = ((unsigned int)u) << 16; return v.f;
}
__device__ __forceinline__ unsigned short f2us(float f) {
  union { float f; unsigned int i; } v; v.f = f;
  unsigned int x = v.i;
  return (unsigned short)((x + 0x7FFFu + ((x >> 16) & 1u)) >> 16);
}
__device__ __forceinline__ s16x8 ld8f(const float* p) {
  f32x4 a = *reinterpret_cast<const f32x4*>(p);
  f32x4 b = *reinterpret_cast<const f32x4*>(p + 4);
  s16x8 r;
  r[0] = (short)f2us(a[0]); r[1] = (short)f2us(a[1]);
  r[2] = (short)f2us(a[2]); r[3] = (short)f2us(a[3]);
  r[4] = (short)f2us(b[0]); r[5] = (short)f2us(b[1]);
  r[6] = (short)f2us(b[2]); r[7] = (short)f2us(b[3]);
  return r;
}
__device__ __forceinline__ float sigm(float x) { return 1.0f / (1.0f + __expf(-x)); }
__device__ __forceinline__ float tanh_f(float x) {
  float e = __expf(-2.0f * fabsf(x));
  float t = (1.0f - e) / (1.0f + e);
  return x < 0.0f ? -t : t;
}
// fast variants for the GRU hot loop (plain C, no asm)
__device__ __forceinline__ float fast_sigm(float x) {
  return __builtin_amdgcn_rcpf(1.0f + __expf(-x));
}
__device__ __forceinline__ float fast_tanh(float y) {
  float yc = fminf(fmaxf(y, -15.0f), 15.0f);
  float e2 = __expf(2.0f * yc);
  return (e2 - 1.0f) * __builtin_amdgcn_rcpf(e2 + 1.0f);
}

// ---------------------------------------------------------------------------
// f32 -> bf16 weight preconversion into ws:
// [0,196608) whh_q | [196608,393216) whh_p | [393216,425984) q_fc1_w |
// [425984,622592) q_attn_in_w
// ---------------------------------------------------------------------------
__global__ __launch_bounds__(256) void conv_k(
    const float* __restrict__ s0, const float* __restrict__ s1,
    const float* __restrict__ s2, const float* __restrict__ s3,
    ushort_t* __restrict__ d) {
  int i = blockIdx.x * 256 + threadIdx.x;
  if (i >= 155648) return;
  long e = (long)i * 4;
  const float* s; long off;
  if (e < 196608) { s = s0; off = e; }
  else if (e < 393216) { s = s1; off = e - 196608; }
  else if (e < 425984) { s = s2; off = e - 393216; }
  else { s = s3; off = e - 425984; }
  f32x4 v = *reinterpret_cast<const f32x4*>(s + off);
  s16x4 r;
  r[0] = (short)f2us(v[0]); r[1] = (short)f2us(v[1]);
  r[2] = (short)f2us(v[2]); r[3] = (short)f2us(v[3]);
  *reinterpret_cast<s16x4*>(d + e) = r;
}

// ---------------------------------------------------------------------------
// Grid GEMM (round-8 structure, NF<=4): out = epi(A[M,K] @ W[N,K]^T + bias)
// grid = (M/128, N/BN, [1|2]). z-batch via (A2,W2,bias2,out2).
// QKV epilogue: col<256 -> q rows (e<8) *0.125 -> qout; col>=256 -> kv.
// ---------------------------------------------------------------------------
template <int BN, int EPI, int ROWSEL, int RELU, int AF32, int WF32, int OF32,
          int QKV, int HB>
__global__ __launch_bounds__(256) void gemm_k(
    const void* __restrict__ A_, const void* __restrict__ W_,
    const float* __restrict__ bias, const int* __restrict__ em,
    void* __restrict__ out_, ushort_t* __restrict__ qout, long row0,
    int M, int N, int K,
    const void* __restrict__ A2_, const void* __restrict__ W2_,
    const float* __restrict__ bias2, void* __restrict__ out2_) {
  constexpr int NF = BN / 32;
  if (A2_ != nullptr && blockIdx.z != 0) {
    A_ = A2_; W_ = W2_; bias = bias2; out_ = out2_;
  }
  const float* Af = (const float*)A_;
  const ushort_t* Ab = (const ushort_t*)A_;
  const float* Wf = (const float*)W_;
  const ushort_t* Wb = (const ushort_t*)W_;
  float* outf = (float*)out_;
  ushort_t* outb = (ushort_t*)out_;
  __shared__ ushort_t As[128 * 40];
  __shared__ ushort_t Ws[BN * 40];
  const int tid = threadIdx.x;
  const int lane = tid & 63;
  const int wid = tid >> 6;
  const int wm = wid & 1, wn = wid >> 1;
  const int m0 = blockIdx.x * 128;
  const int n0 = blockIdx.y * BN;
  const int fr = lane & 15;
  const int kb = (lane >> 4) * 8;
  const int rb = (lane >> 4) * 4;

  f32x4 acc[4][NF];
#pragma unroll
  for (int i = 0; i < 4; i++)
#pragma unroll
    for (int j = 0; j < NF; j++) acc[i][j] = (f32x4){0.f, 0.f, 0.f, 0.f};

  for (int k0 = 0; k0 < K; k0 += 32) {
    __syncthreads();
    for (int c = tid; c < 512; c += 256) {
      int row = c >> 2, kc = (c & 3) * 8;
      int gr = m0 + row;
      long ar = ROWSEL ? ((long)(gr >> 3) * 64 + (gr & 7)) : (long)gr;
      s16x8 vv;
      if (AF32) vv = ld8f(&Af[ar * (long)K + k0 + kc]);
      else vv = *reinterpret_cast<const s16x8*>(&Ab[ar * (long)K + k0 + kc]);
      *reinterpret_cast<s16x8*>(&As[row * 40 + kc]) = vv;
    }
    for (int c = tid; c < BN * 4; c += 256) {
      int row = c >> 2, kc = (c & 3) * 8;
      s16x8 wv;
      if (WF32) wv = ld8f(&Wf[(long)(n0 + row) * K + k0 + kc]);
      else wv = *reinterpret_cast<const s16x8*>(&Wb[(long)(n0 + row) * K + k0 + kc]);
      *reinterpret_cast<s16x8*>(&Ws[row * 40 + kc]) = wv;
    }
    __syncthreads();
    s16x8 af[4], wf[NF];
#pragma unroll
    for (int mi = 0; mi < 4; mi++)
      af[mi] = *reinterpret_cast<const s16x8*>(&As[(wm * 64 + mi * 16 + fr) * 40 + kb]);
#pragma unroll
    for (int ni = 0; ni < NF; ni++)
      wf[ni] = *reinterpret_cast<const s16x8*>(&Ws[(wn * (BN / 2) + ni * 16 + fr) * 40 + kb]);
#pragma unroll
    for (int mi = 0; mi < 4; mi++)
#pragma unroll
      for (int ni = 0; ni < NF; ni++) acc[mi][ni] = MFMA16(af[mi], wf[ni], acc[mi][ni]);
  }

#pragma unroll
  for (int ni = 0; ni < NF; ni++) {
    int col = n0 + wn * (BN / 2) + ni * 16 + fr;
    float bv = HB ? bias[col] : 0.0f;
#pragma unroll
    for (int mi = 0; mi < 4; mi++) {
#pragma unroll
      for (int rr = 0; rr < 4; rr++) {
        int row = m0 + wm * 64 + mi * 16 + rb + rr;
        float v = acc[mi][ni][rr] + bv;
        if (RELU) v = fmaxf(v, 0.0f);
        if (EPI == 2 || EPI == 3) {
          if (em[(long)(row >> 3) * 64 + (row & 7)] != 0) v = (EPI == 2) ? 0.0f : -1.0e10f;
        }
        if (QKV) {
          long grow = row0 + row;
          int e = (int)(grow & 63);
          if (col < 256) {
            if (e < 8) qout[((grow >> 6) * 8 + e) * 256 + col] = f2us(v * 0.125f);
          } else {
            outb[(long)row * 512 + (col - 256)] = f2us(v);
          }
        } else if (OF32) {
          outf[(long)row * N + col] = v;
        } else {
          outb[(long)row * N + col] = f2us(v);
        }
      }
    }
  }
}

// ---------------------------------------------------------------------------
// Attention core (unchanged, passing): one block per batch.
// ---------------------------------------------------------------------------
__global__ __launch_bounds__(512) void attn2_k(
    const ushort_t* __restrict__ kv, const ushort_t* __restrict__ qbuf,
    const int* __restrict__ obs, ushort_t* __restrict__ attn_out, int b0) {
  __shared__ ushort_t qs[16 * 264];
  __shared__ ushort_t ks[64 * 264];
  __shared__ ushort_t vs[64 * 264];
  __shared__ float lg[32 * 66];
  __shared__ int oms[512];

  const int b_loc = blockIdx.x;
  const long b = b0 + b_loc;
  const int tid = threadIdx.x;
  const int lane = tid & 63;
  const int w = tid >> 6;
  const int fr = lane & 15, kb = (lane >> 4) * 8, rb = (lane >> 4) * 4;

  oms[tid] = obs[b * 4096 + tid];
  {
    int row = tid >> 5, cc = (tid & 31) * 8;
    if (tid < 256) {
      *reinterpret_cast<s16x8*>(&qs[row * 264 + cc]) =
          *reinterpret_cast<const s16x8*>(&qbuf[(b * 8 + row) * 256 + cc]);
    } else {
      *reinterpret_cast<s16x8*>(&qs[row * 264 + cc]) = (s16x8){0,0,0,0,0,0,0,0};
    }
  }
  for (int i = 0; i < 4; i++) {
    int e = i * 16 + (tid >> 5);
    int cc = (tid & 31) * 8;
    const ushort_t* src = &kv[((long)(b_loc * 64 + e)) * 512];
    *reinterpret_cast<s16x8*>(&ks[e * 264 + cc]) =
        *reinterpret_cast<const s16x8*>(&src[cc]);
    *reinterpret_cast<s16x8*>(&vs[e * 264 + cc]) =
        *reinterpret_cast<const s16x8*>(&src[256 + cc]);
  }
  __syncthreads();

  {
    const int h = w >> 1, np = w & 1;
    f32x4 lacc[2];
    lacc[0] = (f32x4){0.f, 0.f, 0.f, 0.f};
    lacc[1] = (f32x4){0.f, 0.f, 0.f, 0.f};
#pragma unroll
    for (int k0 = 0; k0 < 64; k0 += 32) {
      s16x8 af = *reinterpret_cast<const s16x8*>(&qs[fr * 264 + h * 64 + k0 + kb]);
#pragma unroll
      for (int j = 0; j < 2; j++) {
        int e0 = (np * 2 + j) * 16;
        s16x8 bf = *reinterpret_cast<const s16x8*>(&ks[(e0 + fr) * 264 + h * 64 + k0 + kb]);
        lacc[j] = MFMA16(af, bf, lacc[j]);
      }
    }
#pragma unroll
    for (int j = 0; j < 2; j++) {
      int e = (np * 2 + j) * 16 + fr;
#pragma unroll
      for (int rr = 0; rr < 4; rr++) {
        int a = rb + rr;
        if (a < 8)
          lg[(a * 4 + h) * 66 + e] = (oms[a * 64 + e] != 0) ? -1.0e30f : lacc[j][rr];
      }
    }
  }
  __syncthreads();

  {
    int ri = tid >> 4, sub = tid & 15;
    float v4[4];
#pragma unroll
    for (int j = 0; j < 4; j++) v4[j] = lg[ri * 66 + sub * 4 + j];
    float m = fmaxf(fmaxf(v4[0], v4[1]), fmaxf(v4[2], v4[3]));
#pragma unroll
    for (int d = 1; d < 16; d <<= 1) m = fmaxf(m, __shfl_xor(m, d));
    bool dead = (m < -5.0e29f);
    float s = 0.0f;
#pragma unroll
    for (int j = 0; j < 4; j++) { v4[j] = __expf(v4[j] - m); s += v4[j]; }
#pragma unroll
    for (int d = 1; d < 16; d <<= 1) s += __shfl_xor(s, d);
    float inv = dead ? 0.0f : (1.0f / s);
#pragma unroll
    for (int j = 0; j < 4; j++) lg[ri * 66 + sub * 4 + j] = v4[j] * inv;
  }
  __syncthreads();

  {
    int a = tid >> 6, d0 = (tid & 63) * 4, h = d0 >> 6;
    const float* wrow = &lg[(a * 4 + h) * 66];
    float facc[4] = {0.f, 0.f, 0.f, 0.f};
    for (int e = 0; e < 64; e++) {
      float wv = wrow[e];
      s16x4 vv = *reinterpret_cast<const s16x4*>(&vs[e * 264 + d0]);
#pragma unroll
      for (int j = 0; j < 4; j++) facc[j] += wv * us2f((unsigned short)vv[j]);
    }
    s16x4 r;
#pragma unroll
    for (int j = 0; j < 4; j++) r[j] = (short)f2us(facc[j]);
    *reinterpret_cast<s16x4*>(&attn_out[(b * 8 + a) * 256 + d0]) = r;
  }
}

// ---------------------------------------------------------------------------
// GRU scan v6 = gru4 (measured 187us) + plain-C diet + gi prefetch:
// - bhh folded into MFMA C-init
// - rcp-based sigmoid / clamped-exp tanh; hn = n + z*(h-n)
// - gi loads for step t+1 issued right AFTER step t's barrier, so the
//   conservative vmcnt drain at the NEXT barrier lands ~500cy after issue
//   (hidden under MFMA+epilogue+staging) instead of ~50cy.
// NO inline asm, NO setprio (both regressed in round 11).
// ---------------------------------------------------------------------------
__global__ __launch_bounds__(1024, 4) void gru6_k(
    const ushort_t* __restrict__ gi_q, const ushort_t* __restrict__ gi_p,
    const ushort_t* __restrict__ whhb_q, const ushort_t* __restrict__ whhb_p,
    const float* __restrict__ bhh_q, const float* __restrict__ bhh_p,
    const float* __restrict__ h0_q, const float* __restrict__ h0_p,
    float* __restrict__ hs_q, float* __restrict__ hs_p) {
  __shared__ ushort_t nw[256 * 256];     // n-gate weights, swizzled, 128KB
  __shared__ ushort_t hls[2][16 * 264];  // double-buffered h staging
  const int bid = blockIdx.x;
  const int mdl = bid >> 4, cg = bid & 15;
  const ushort_t* gi = mdl ? gi_p : gi_q;
  const ushort_t* whh = mdl ? whhb_p : whhb_q;
  const float* bhh = mdl ? bhh_p : bhh_q;
  const float* h0 = mdl ? h0_p : h0_q;
  float* hs = mdl ? hs_p : hs_q;

  const int tid = threadIdx.x;
  const int lane = tid & 63, w = tid >> 6;
  const int fr = lane & 15, kb = (lane >> 4) * 8, rb = (lane >> 4) * 4;
  const int col = w * 16 + fr;

  s16x8 wrz[2][8];
#pragma unroll
  for (int g = 0; g < 2; g++)
#pragma unroll
    for (int ks = 0; ks < 8; ks++)
      wrz[g][ks] = *reinterpret_cast<const s16x8*>(
          &whh[(g * 256 + col) * 256 + ks * 32 + kb]);

  char* nwb = (char*)nw;
  for (int c = tid; c < 8192; c += 1024) {
    int row = c >> 5, kc = (c & 31) * 8;
    *reinterpret_cast<s16x8*>(nwb + row * 512 + ((kc * 2) ^ ((row & 7) << 4))) =
        *reinterpret_cast<const s16x8*>(&whh[(512 + row) * 256 + kc]);
  }

  int nwaddr[8];
#pragma unroll
  for (int ks = 0; ks < 8; ks++)
    nwaddr[ks] = col * 512 + (((ks * 32 + kb) * 2) ^ ((col & 7) << 4));

  float h[4], bh[3];
#pragma unroll
  for (int rr = 0; rr < 4; rr++) h[rr] = h0[(cg * 16 + rb + rr) * 256 + col];
#pragma unroll
  for (int g = 0; g < 3; g++) bh[g] = bhh[g * 256 + col];

  const int chain0 = cg * 16 + rb;
  const long r0 = (long)(chain0 >> 3) * 512 + (chain0 & 7);
  const ushort_t* gp0 = gi + r0 * 768 + col;
  float* hp0 = hs + r0 * 256 + col;

  // preload gi for t=0
  float gva[3][4], gvb[3][4];
#pragma unroll
  for (int rr = 0; rr < 4; rr++) {
    gva[0][rr] = us2f(gp0[rr * 768]);
    gva[1][rr] = us2f(gp0[rr * 768 + 256]);
    gva[2][rr] = us2f(gp0[rr * 768 + 512]);
  }
  gp0 += 6144;

#define GRU_STEP(BUF, GCUR, GNXT, DO_PF)                                       \
  {                                                                            \
    _Pragma("unroll") for (int rr = 0; rr < 4; rr++)                           \
        hls[BUF][(rb + rr) * 264 + col] = f2us(h[rr]);                         \
    __syncthreads();                                                           \
    if (DO_PF) {                                                               \
      _Pragma("unroll") for (int rr = 0; rr < 4; rr++) {                       \
        GNXT[0][rr] = us2f(gp0[rr * 768]);                                     \
        GNXT[1][rr] = us2f(gp0[rr * 768 + 256]);                               \
        GNXT[2][rr] = us2f(gp0[rr * 768 + 512]);                               \
      }                                                                        \
      gp0 += 6144;                                                             \
    }                                                                          \
    f32x4 acc[3];                                                              \
    _Pragma("unroll") for (int i = 0; i < 3; i++)                              \
        acc[i] = (f32x4){bh[i], bh[i], bh[i], bh[i]};                          \
    _Pragma("unroll") for (int ks = 0; ks < 8; ks++) {                         \
      s16x8 a = *reinterpret_cast<const s16x8*>(                               \
          &hls[BUF][fr * 264 + ks * 32 + kb]);                                 \
      acc[0] = MFMA16(a, wrz[0][ks], acc[0]);                                  \
      acc[1] = MFMA16(a, wrz[1][ks], acc[1]);                                  \
      s16x8 bn = *reinterpret_cast<const s16x8*>(nwb + nwaddr[ks]);            \
      acc[2] = MFMA16(a, bn, acc[2]);                                          \
    }                                                                          \
    _Pragma("unroll") for (int rr = 0; rr < 4; rr++) {                         \
      float r_ = fast_sigm(GCUR[0][rr] + acc[0][rr]);                          \
      float z_ = fast_sigm(GCUR[1][rr] + acc[1][rr]);                          \
      float n_ = fast_tanh(GCUR[2][rr] + r_ * acc[2][rr]);                     \
      float hn = n_ + z_ * (h[rr] - n_);                                       \
      h[rr] = hn;                                                              \
      hp0[rr * 256] = hn;                                                      \
    }                                                                          \
    hp0 += 2048;                                                               \
  }

  for (int t2 = 0; t2 < 32; t2++) {
    GRU_STEP(0, gva, gvb, 1)
    GRU_STEP(1, gvb, gva, (t2 != 31))
  }
#undef GRU_STEP
}

// ---------------------------------------------------------------------------
extern "C" void kernel_launch(void* const* d_in, const int* in_sizes, int n_in,
                              void* d_out, int out_size, void* d_ws, size_t ws_size,
                              hipStream_t stream) {
  (void)in_sizes; (void)n_in; (void)out_size; (void)ws_size;

  const float* entities = (const float*)d_in[0];
  const int* obs = (const int*)d_in[1];
  const int* em = (const int*)d_in[2];
  const float* hidq = (const float*)d_in[3];
  const float* hidp = (const float*)d_in[4];
  const float* q_fc1_w = (const float*)d_in[5];
  const float* q_fc1_b = (const float*)d_in[6];
  const float* q_fc2_w = (const float*)d_in[7];
  const float* q_fc2_b = (const float*)d_in[8];
  const float* q_wih = (const float*)d_in[9];
  const float* q_whh = (const float*)d_in[10];
  const float* q_bih = (const float*)d_in[11];
  const float* q_bhh = (const float*)d_in[12];
  const float* q_fcq_w = (const float*)d_in[13];
  const float* q_fcq_b = (const float*)d_in[14];
  const float* q_fcpi_w = (const float*)d_in[15];
  const float* q_fcpi_b = (const float*)d_in[16];
  const float* p_fc1_w = (const float*)d_in[17];
  const float* p_fc1_b = (const float*)d_in[18];
  const float* p_fc2_w = (const float*)d_in[19];
  const float* p_fc2_b = (const float*)d_in[20];
  const float* p_wih = (const float*)d_in[21];
  const float* p_whh = (const float*)d_in[22];
  const float* p_bih = (const float*)d_in[23];
  const float* p_bhh = (const float*)d_in[24];
  const float* p_fcpi_w = (const float*)d_in[27];
  const float* p_fcpi_b = (const float*)d_in[28];
  const float* inw = (const float*)d_in[29];
  const float* outw = (const float*)d_in[30];
  const float* outb = (const float*)d_in[31];

  // ws layout (bf16 elems) — round-10 proven layout, all buffers distinct.
  ushort_t* ws = (ushort_t*)d_ws;
  ushort_t* qbuf = ws;                  // [0, 4.19M)
  ushort_t* attn = ws + 4194304l;       // [4.19M, 8.39M)
  ushort_t* x1c  = ws + 8388608l;       // [8.39M, 16.78M)  chunk x1
  ushort_t* kvc  = ws + 16777216l;      // [16.78M, 33.55M) chunk kv
  ushort_t* wcv  = ws + 33554432l;      // converted weights (622,592)
  ushort_t* wbq = wcv;                  // whh_q bf16
  ushort_t* wbp = wcv + 196608l;        // whh_p bf16
  ushort_t* wf1 = wcv + 393216l;        // q_fc1_w bf16
  ushort_t* win = wcv + 425984l;        // q_attn_in_w bf16
  ushort_t* x2b = ws + 35651584l;       // distinct
  ushort_t* x3q = ws + 39845888l;
  ushort_t* x1p = ws + 44040192l;
  ushort_t* x3p = ws + 48234496l;
  ushort_t* giq = ws + 52428800l;       // 12,582,912
  ushort_t* gip = ws + 65011712l;       // 12,582,912 (end 77,594,624)

  float* out = (float*)d_out;
  float* o_q = out;
  float* o_pi = out + 1048576l;
  float* o_piA = out + 2097152l;
  float* o_hq = out + 3145728l;
  float* o_hp = out + 7340032l;

  const int nc = 4, CB = 512;
  const long MR = (long)CB * 64;  // 32768 rows per chunk
  const void* NUL = nullptr;

  // 0) pre-convert hot weights to bf16
  conv_k<<<608, 256, 0, stream>>>(q_whh, p_whh, q_fc1_w, inw, wcv);

  // 1) attention path, chunked so kv stays L3-resident (round-8 configs)
  for (int c = 0; c < nc; c++) {
    gemm_k<128, 0, 0, 1, 1, 0, 0, 0, 1><<<dim3(256, 2), 256, 0, stream>>>(
        entities + (long)c * MR * 128, wf1, q_fc1_b, em, x1c, nullptr, 0,
        (int)MR, 256, 128, NUL, NUL, nullptr, nullptr);
    gemm_k<128, 0, 0, 0, 0, 0, 0, 1, 0><<<dim3(256, 6), 256, 0, stream>>>(
        x1c, win, nullptr, em, kvc, qbuf, (long)c * MR, (int)MR, 768, 256,
        NUL, NUL, nullptr, nullptr);
    attn2_k<<<CB, 512, 0, stream>>>(kvc, qbuf, obs, attn, c * CB);
  }
  // 2) x2 = mask0(attn @ outw^T + outb)
  gemm_k<128, 2, 0, 0, 0, 1, 0, 0, 1><<<dim3(128, 2), 256, 0, stream>>>(
      attn, outw, outb, em, x2b, nullptr, 0, 16384, 256, 256,
      NUL, NUL, nullptr, nullptr);
  // 3) x1p = relu(ent[:, :8] @ fc1^T + b)
  gemm_k<128, 0, 1, 1, 1, 1, 0, 0, 1><<<dim3(128, 2), 256, 0, stream>>>(
      entities, p_fc1_w, p_fc1_b, em, x1p, nullptr, 0, 16384, 256, 128,
      NUL, NUL, nullptr, nullptr);
  // 4) z-batched x3: {x3q = relu(x2@q_fc2)} | {x3p = relu(x1p@p_fc2)}
  gemm_k<128, 0, 0, 1, 0, 1, 0, 0, 1><<<dim3(128, 2, 2), 256, 0, stream>>>(
      x2b, q_fc2_w, q_fc2_b, em, x3q, nullptr, 0, 16384, 256, 256,
      x1p, p_fc2_w, p_fc2_b, x3p);
  // 5) z-batched gi: {giq = x3q@q_wih + bih} | {gip = x3p@p_wih + bih}
  gemm_k<128, 0, 0, 0, 0, 1, 0, 0, 1><<<dim3(128, 6, 2), 256, 0, stream>>>(
      x3q, q_wih, q_bih, em, giq, nullptr, 0, 16384, 768, 256,
      x3p, p_wih, p_bih, gip);
  // 6) GRU scan v6
  gru6_k<<<32, 1024, 0, stream>>>(giq, gip, wbq, wbp, q_bhh, p_bhh, hidq, hidp,
                                  o_hq, o_hp);
  // 7) heads: o_q, then z-batched {pi from h_q} | {pi_avg from h_pi}
  gemm_k<64, 2, 0, 0, 1, 1, 1, 0, 1><<<dim3(128, 1), 256, 0, stream>>>(
      o_hq, q_fcq_w, q_fcq_b, em, o_q, nullptr, 0, 16384, 64, 256,
      NUL, NUL, nullptr, nullptr);
  gemm_k<64, 3, 0, 0, 1, 1, 1, 0, 1><<<dim3(128, 1, 2), 256, 0, stream>>>(
      o_hq, q_fcpi_w, q_fcpi_b, em, o_pi, nullptr, 0, 16384, 64, 256,
      o_hp, p_fcpi_w, p_fcpi_b, o_piA);
}

// Round 13
// 593.159 us; speedup vs baseline: 1.1326x; 1.0952x over previous
//
#include <hip/hip_runtime.h>

typedef unsigned short ushort_t;  // raw bf16 bits
typedef __attribute__((ext_vector_type(4))) float f32x4;
typedef __attribute__((ext_vector_type(8))) short s16x8;
typedef __attribute__((ext_vector_type(4))) short s16x4;

#define MFMA16(a, b, c) __builtin_amdgcn_mfma_f32_16x16x32_bf16((a), (b), (c), 0, 0, 0)

__device__ __forceinline__ float us2f(unsigned short u) {
  union { unsigned int i; float f; } v; v.i = ((unsigned int)u) << 16; return v.f;
}
__device__ __forceinline__ unsigned short f2us(float f) {
  union { float f; unsigned int i; } v; v.f = f;
  unsigned int x = v.i;
  return (unsigned short)((x + 0x7FFFu + ((x >> 16) & 1u)) >> 16);
}
__device__ __forceinline__ s16x8 ld8f(const float* p) {
  f32x4 a = *reinterpret_cast<const f32x4*>(p);
  f32x4 b = *reinterpret_cast<const f32x4*>(p + 4);
  s16x8 r;
  r[0] = (short)f2us(a[0]); r[1] = (short)f2us(a[1]);
  r[2] = (short)f2us(a[2]); r[3] = (short)f2us(a[3]);
  r[4] = (short)f2us(b[0]); r[5] = (short)f2us(b[1]);
  r[6] = (short)f2us(b[2]); r[7] = (short)f2us(b[3]);
  return r;
}
__device__ __forceinline__ float sigm(float x) { return 1.0f / (1.0f + __expf(-x)); }
__device__ __forceinline__ float tanh_f(float x) {
  float e = __expf(-2.0f * fabsf(x));
  float t = (1.0f - e) / (1.0f + e);
  return x < 0.0f ? -t : t;
}

// ---------------------------------------------------------------------------
// f32 -> bf16 weight preconversion into ws:
// [0,196608) whh_q | [196608,393216) whh_p | [393216,425984) q_fc1_w |
// [425984,622592) q_attn_in_w
// ---------------------------------------------------------------------------
__global__ __launch_bounds__(256) void conv_k(
    const float* __restrict__ s0, const float* __restrict__ s1,
    const float* __restrict__ s2, const float* __restrict__ s3,
    ushort_t* __restrict__ d) {
  int i = blockIdx.x * 256 + threadIdx.x;
  if (i >= 155648) return;
  long e = (long)i * 4;
  const float* s; long off;
  if (e < 196608) { s = s0; off = e; }
  else if (e < 393216) { s = s1; off = e - 196608; }
  else if (e < 425984) { s = s2; off = e - 393216; }
  else { s = s3; off = e - 425984; }
  f32x4 v = *reinterpret_cast<const f32x4*>(s + off);
  s16x4 r;
  r[0] = (short)f2us(v[0]); r[1] = (short)f2us(v[1]);
  r[2] = (short)f2us(v[2]); r[3] = (short)f2us(v[3]);
  *reinterpret_cast<s16x4*>(d + e) = r;
}

// ---------------------------------------------------------------------------
// Grid GEMM (round-8 structure, NF<=4): out = epi(A[M,K] @ W[N,K]^T + bias)
// grid = (M/128, N/BN, [1|2]). z-batch via (A2,W2,bias2,out2).
// QKV epilogue: col<256 -> q rows (e<8) *0.125 -> qout; col>=256 -> kv.
// ---------------------------------------------------------------------------
template <int BN, int EPI, int ROWSEL, int RELU, int AF32, int WF32, int OF32,
          int QKV, int HB>
__global__ __launch_bounds__(256) void gemm_k(
    const void* __restrict__ A_, const void* __restrict__ W_,
    const float* __restrict__ bias, const int* __restrict__ em,
    void* __restrict__ out_, ushort_t* __restrict__ qout, long row0,
    int M, int N, int K,
    const void* __restrict__ A2_, const void* __restrict__ W2_,
    const float* __restrict__ bias2, void* __restrict__ out2_) {
  constexpr int NF = BN / 32;
  if (A2_ != nullptr && blockIdx.z != 0) {
    A_ = A2_; W_ = W2_; bias = bias2; out_ = out2_;
  }
  const float* Af = (const float*)A_;
  const ushort_t* Ab = (const ushort_t*)A_;
  const float* Wf = (const float*)W_;
  const ushort_t* Wb = (const ushort_t*)W_;
  float* outf = (float*)out_;
  ushort_t* outb = (ushort_t*)out_;
  __shared__ ushort_t As[128 * 40];
  __shared__ ushort_t Ws[BN * 40];
  const int tid = threadIdx.x;
  const int lane = tid & 63;
  const int wid = tid >> 6;
  const int wm = wid & 1, wn = wid >> 1;
  const int m0 = blockIdx.x * 128;
  const int n0 = blockIdx.y * BN;
  const int fr = lane & 15;
  const int kb = (lane >> 4) * 8;
  const int rb = (lane >> 4) * 4;

  f32x4 acc[4][NF];
#pragma unroll
  for (int i = 0; i < 4; i++)
#pragma unroll
    for (int j = 0; j < NF; j++) acc[i][j] = (f32x4){0.f, 0.f, 0.f, 0.f};

  for (int k0 = 0; k0 < K; k0 += 32) {
    __syncthreads();
    for (int c = tid; c < 512; c += 256) {
      int row = c >> 2, kc = (c & 3) * 8;
      int gr = m0 + row;
      long ar = ROWSEL ? ((long)(gr >> 3) * 64 + (gr & 7)) : (long)gr;
      s16x8 vv;
      if (AF32) vv = ld8f(&Af[ar * (long)K + k0 + kc]);
      else vv = *reinterpret_cast<const s16x8*>(&Ab[ar * (long)K + k0 + kc]);
      *reinterpret_cast<s16x8*>(&As[row * 40 + kc]) = vv;
    }
    for (int c = tid; c < BN * 4; c += 256) {
      int row = c >> 2, kc = (c & 3) * 8;
      s16x8 wv;
      if (WF32) wv = ld8f(&Wf[(long)(n0 + row) * K + k0 + kc]);
      else wv = *reinterpret_cast<const s16x8*>(&Wb[(long)(n0 + row) * K + k0 + kc]);
      *reinterpret_cast<s16x8*>(&Ws[row * 40 + kc]) = wv;
    }
    __syncthreads();
    s16x8 af[4], wf[NF];
#pragma unroll
    for (int mi = 0; mi < 4; mi++)
      af[mi] = *reinterpret_cast<const s16x8*>(&As[(wm * 64 + mi * 16 + fr) * 40 + kb]);
#pragma unroll
    for (int ni = 0; ni < NF; ni++)
      wf[ni] = *reinterpret_cast<const s16x8*>(&Ws[(wn * (BN / 2) + ni * 16 + fr) * 40 + kb]);
#pragma unroll
    for (int mi = 0; mi < 4; mi++)
#pragma unroll
      for (int ni = 0; ni < NF; ni++) acc[mi][ni] = MFMA16(af[mi], wf[ni], acc[mi][ni]);
  }

#pragma unroll
  for (int ni = 0; ni < NF; ni++) {
    int col = n0 + wn * (BN / 2) + ni * 16 + fr;
    float bv = HB ? bias[col] : 0.0f;
#pragma unroll
    for (int mi = 0; mi < 4; mi++) {
#pragma unroll
      for (int rr = 0; rr < 4; rr++) {
        int row = m0 + wm * 64 + mi * 16 + rb + rr;
        float v = acc[mi][ni][rr] + bv;
        if (RELU) v = fmaxf(v, 0.0f);
        if (EPI == 2 || EPI == 3) {
          if (em[(long)(row >> 3) * 64 + (row & 7)] != 0) v = (EPI == 2) ? 0.0f : -1.0e10f;
        }
        if (QKV) {
          long grow = row0 + row;
          int e = (int)(grow & 63);
          if (col < 256) {
            if (e < 8) qout[((grow >> 6) * 8 + e) * 256 + col] = f2us(v * 0.125f);
          } else {
            outb[(long)row * 512 + (col - 256)] = f2us(v);
          }
        } else if (OF32) {
          outf[(long)row * N + col] = v;
        } else {
          outb[(long)row * N + col] = f2us(v);
        }
      }
    }
  }
}

// ---------------------------------------------------------------------------
// Attention core (unchanged, passing): one block per batch.
// ---------------------------------------------------------------------------
__global__ __launch_bounds__(512) void attn2_k(
    const ushort_t* __restrict__ kv, const ushort_t* __restrict__ qbuf,
    const int* __restrict__ obs, ushort_t* __restrict__ attn_out, int b0) {
  __shared__ ushort_t qs[16 * 264];
  __shared__ ushort_t ks[64 * 264];
  __shared__ ushort_t vs[64 * 264];
  __shared__ float lg[32 * 66];
  __shared__ int oms[512];

  const int b_loc = blockIdx.x;
  const long b = b0 + b_loc;
  const int tid = threadIdx.x;
  const int lane = tid & 63;
  const int w = tid >> 6;
  const int fr = lane & 15, kb = (lane >> 4) * 8, rb = (lane >> 4) * 4;

  oms[tid] = obs[b * 4096 + tid];
  {
    int row = tid >> 5, cc = (tid & 31) * 8;
    if (tid < 256) {
      *reinterpret_cast<s16x8*>(&qs[row * 264 + cc]) =
          *reinterpret_cast<const s16x8*>(&qbuf[(b * 8 + row) * 256 + cc]);
    } else {
      *reinterpret_cast<s16x8*>(&qs[row * 264 + cc]) = (s16x8){0,0,0,0,0,0,0,0};
    }
  }
  for (int i = 0; i < 4; i++) {
    int e = i * 16 + (tid >> 5);
    int cc = (tid & 31) * 8;
    const ushort_t* src = &kv[((long)(b_loc * 64 + e)) * 512];
    *reinterpret_cast<s16x8*>(&ks[e * 264 + cc]) =
        *reinterpret_cast<const s16x8*>(&src[cc]);
    *reinterpret_cast<s16x8*>(&vs[e * 264 + cc]) =
        *reinterpret_cast<const s16x8*>(&src[256 + cc]);
  }
  __syncthreads();

  {
    const int h = w >> 1, np = w & 1;
    f32x4 lacc[2];
    lacc[0] = (f32x4){0.f, 0.f, 0.f, 0.f};
    lacc[1] = (f32x4){0.f, 0.f, 0.f, 0.f};
#pragma unroll
    for (int k0 = 0; k0 < 64; k0 += 32) {
      s16x8 af = *reinterpret_cast<const s16x8*>(&qs[fr * 264 + h * 64 + k0 + kb]);
#pragma unroll
      for (int j = 0; j < 2; j++) {
        int e0 = (np * 2 + j) * 16;
        s16x8 bf = *reinterpret_cast<const s16x8*>(&ks[(e0 + fr) * 264 + h * 64 + k0 + kb]);
        lacc[j] = MFMA16(af, bf, lacc[j]);
      }
    }
#pragma unroll
    for (int j = 0; j < 2; j++) {
      int e = (np * 2 + j) * 16 + fr;
#pragma unroll
      for (int rr = 0; rr < 4; rr++) {
        int a = rb + rr;
        if (a < 8)
          lg[(a * 4 + h) * 66 + e] = (oms[a * 64 + e] != 0) ? -1.0e30f : lacc[j][rr];
      }
    }
  }
  __syncthreads();

  {
    int ri = tid >> 4, sub = tid & 15;
    float v4[4];
#pragma unroll
    for (int j = 0; j < 4; j++) v4[j] = lg[ri * 66 + sub * 4 + j];
    float m = fmaxf(fmaxf(v4[0], v4[1]), fmaxf(v4[2], v4[3]));
#pragma unroll
    for (int d = 1; d < 16; d <<= 1) m = fmaxf(m, __shfl_xor(m, d));
    bool dead = (m < -5.0e29f);
    float s = 0.0f;
#pragma unroll
    for (int j = 0; j < 4; j++) { v4[j] = __expf(v4[j] - m); s += v4[j]; }
#pragma unroll
    for (int d = 1; d < 16; d <<= 1) s += __shfl_xor(s, d);
    float inv = dead ? 0.0f : (1.0f / s);
#pragma unroll
    for (int j = 0; j < 4; j++) lg[ri * 66 + sub * 4 + j] = v4[j] * inv;
  }
  __syncthreads();

  {
    int a = tid >> 6, d0 = (tid & 63) * 4, h = d0 >> 6;
    const float* wrow = &lg[(a * 4 + h) * 66];
    float facc[4] = {0.f, 0.f, 0.f, 0.f};
    for (int e = 0; e < 64; e++) {
      float wv = wrow[e];
      s16x4 vv = *reinterpret_cast<const s16x4*>(&vs[e * 264 + d0]);
#pragma unroll
      for (int j = 0; j < 4; j++) facc[j] += wv * us2f((unsigned short)vv[j]);
    }
    s16x4 r;
#pragma unroll
    for (int j = 0; j < 4; j++) r[j] = (short)f2us(facc[j]);
    *reinterpret_cast<s16x4*>(&attn_out[(b * 8 + a) * 256 + d0]) = r;
  }
}

// ---------------------------------------------------------------------------
// GRU scan v7 = gru4 (measured 187us) with ONE change: the hs store of step
// t's result is DEFERRED to just after step t+1's barrier. At that point the
// value is still live in h[] (it was just staged to LDS), so no extra regs;
// the store then has a full MFMA+epilogue+staging (~2us) to complete before
// the next barrier's conservative vmcnt(0) drain, instead of ~50 cycles.
// Everything else (activations, acc init, gi load placement) is gru4 verbatim.
// ---------------------------------------------------------------------------
__global__ __launch_bounds__(1024, 4) void gru7_k(
    const ushort_t* __restrict__ gi_q, const ushort_t* __restrict__ gi_p,
    const ushort_t* __restrict__ whhb_q, const ushort_t* __restrict__ whhb_p,
    const float* __restrict__ bhh_q, const float* __restrict__ bhh_p,
    const float* __restrict__ h0_q, const float* __restrict__ h0_p,
    float* __restrict__ hs_q, float* __restrict__ hs_p) {
  __shared__ ushort_t nw[256 * 256];     // n-gate weights, swizzled, 128KB
  __shared__ ushort_t hls[2][16 * 264];  // double-buffered h staging
  const int bid = blockIdx.x;
  const int mdl = bid >> 4, cg = bid & 15;
  const ushort_t* gi = mdl ? gi_p : gi_q;
  const ushort_t* whh = mdl ? whhb_p : whhb_q;
  const float* bhh = mdl ? bhh_p : bhh_q;
  const float* h0 = mdl ? h0_p : h0_q;
  float* hs = mdl ? hs_p : hs_q;

  const int tid = threadIdx.x;
  const int lane = tid & 63, w = tid >> 6;
  const int fr = lane & 15, kb = (lane >> 4) * 8, rb = (lane >> 4) * 4;
  const int col = w * 16 + fr;

  s16x8 wrz[2][8];
#pragma unroll
  for (int g = 0; g < 2; g++)
#pragma unroll
    for (int ks = 0; ks < 8; ks++)
      wrz[g][ks] = *reinterpret_cast<const s16x8*>(
          &whh[(g * 256 + col) * 256 + ks * 32 + kb]);

  char* nwb = (char*)nw;
  for (int c = tid; c < 8192; c += 1024) {
    int row = c >> 5, kc = (c & 31) * 8;
    *reinterpret_cast<s16x8*>(nwb + row * 512 + ((kc * 2) ^ ((row & 7) << 4))) =
        *reinterpret_cast<const s16x8*>(&whh[(512 + row) * 256 + kc]);
  }

  int nwaddr[8];
#pragma unroll
  for (int ks = 0; ks < 8; ks++)
    nwaddr[ks] = col * 512 + (((ks * 32 + kb) * 2) ^ ((col & 7) << 4));

  float h[4], bh[3];
#pragma unroll
  for (int rr = 0; rr < 4; rr++) h[rr] = h0[(cg * 16 + rb + rr) * 256 + col];
#pragma unroll
  for (int g = 0; g < 3; g++) bh[g] = bhh[g * 256 + col];

  const int chain0 = cg * 16 + rb;
  const long r0 = (long)(chain0 >> 3) * 512 + (chain0 & 7);
  const ushort_t* gp0 = gi + r0 * 768 + col;
  float* hp_st = hs + r0 * 256 + col;  // lagging store pointer (slot t-1)

// DO_ST: store h (== step t-1's result, just re-staged to LDS) after the
// barrier; its vmcnt drain happens at the NEXT barrier, a full step later.
#define GRU_STEP(BUF, DO_ST)                                                   \
  {                                                                            \
    float gv[3][4];                                                            \
    _Pragma("unroll") for (int rr = 0; rr < 4; rr++) {                         \
      gv[0][rr] = us2f(gp0[rr * 768]);                                         \
      gv[1][rr] = us2f(gp0[rr * 768 + 256]);                                   \
      gv[2][rr] = us2f(gp0[rr * 768 + 512]);                                   \
    }                                                                          \
    gp0 += 6144;                                                               \
    _Pragma("unroll") for (int rr = 0; rr < 4; rr++)                           \
        hls[BUF][(rb + rr) * 264 + col] = f2us(h[rr]);                         \
    __syncthreads();                                                           \
    if (DO_ST) {                                                               \
      _Pragma("unroll") for (int rr = 0; rr < 4; rr++)                         \
          hp_st[rr * 256] = h[rr];                                             \
      hp_st += 2048;                                                           \
    }                                                                          \
    f32x4 acc[3];                                                              \
    _Pragma("unroll") for (int i = 0; i < 3; i++)                              \
        acc[i] = (f32x4){0.f, 0.f, 0.f, 0.f};                                  \
    _Pragma("unroll") for (int ks = 0; ks < 8; ks++) {                         \
      s16x8 a = *reinterpret_cast<const s16x8*>(                               \
          &hls[BUF][fr * 264 + ks * 32 + kb]);                                 \
      acc[0] = MFMA16(a, wrz[0][ks], acc[0]);                                  \
      acc[1] = MFMA16(a, wrz[1][ks], acc[1]);                                  \
      s16x8 bn = *reinterpret_cast<const s16x8*>(nwb + nwaddr[ks]);            \
      acc[2] = MFMA16(a, bn, acc[2]);                                          \
    }                                                                          \
    _Pragma("unroll") for (int rr = 0; rr < 4; rr++) {                         \
      float r_ = sigm(gv[0][rr] + acc[0][rr] + bh[0]);                         \
      float z_ = sigm(gv[1][rr] + acc[1][rr] + bh[1]);                         \
      float n_ = tanh_f(gv[2][rr] + r_ * (acc[2][rr] + bh[2]));                \
      float hn = (1.0f - z_) * n_ + z_ * h[rr];                                \
      h[rr] = hn;                                                              \
    }                                                                          \
  }

  // t = 0 (no deferred store yet)
  GRU_STEP(0, 0)
  // t = 1..62 (31 pairs)
  for (int t2 = 0; t2 < 31; t2++) {
    GRU_STEP(1, 1)
    GRU_STEP(0, 1)
  }
  // t = 63
  GRU_STEP(1, 1)
#undef GRU_STEP
  // final state (t=63's result) -> slot 63
#pragma unroll
  for (int rr = 0; rr < 4; rr++) hp_st[rr * 256] = h[rr];
}

// ---------------------------------------------------------------------------
extern "C" void kernel_launch(void* const* d_in, const int* in_sizes, int n_in,
                              void* d_out, int out_size, void* d_ws, size_t ws_size,
                              hipStream_t stream) {
  (void)in_sizes; (void)n_in; (void)out_size; (void)ws_size;

  const float* entities = (const float*)d_in[0];
  const int* obs = (const int*)d_in[1];
  const int* em = (const int*)d_in[2];
  const float* hidq = (const float*)d_in[3];
  const float* hidp = (const float*)d_in[4];
  const float* q_fc1_w = (const float*)d_in[5];
  const float* q_fc1_b = (const float*)d_in[6];
  const float* q_fc2_w = (const float*)d_in[7];
  const float* q_fc2_b = (const float*)d_in[8];
  const float* q_wih = (const float*)d_in[9];
  const float* q_whh = (const float*)d_in[10];
  const float* q_bih = (const float*)d_in[11];
  const float* q_bhh = (const float*)d_in[12];
  const float* q_fcq_w = (const float*)d_in[13];
  const float* q_fcq_b = (const float*)d_in[14];
  const float* q_fcpi_w = (const float*)d_in[15];
  const float* q_fcpi_b = (const float*)d_in[16];
  const float* p_fc1_w = (const float*)d_in[17];
  const float* p_fc1_b = (const float*)d_in[18];
  const float* p_fc2_w = (const float*)d_in[19];
  const float* p_fc2_b = (const float*)d_in[20];
  const float* p_wih = (const float*)d_in[21];
  const float* p_whh = (const float*)d_in[22];
  const float* p_bih = (const float*)d_in[23];
  const float* p_bhh = (const float*)d_in[24];
  const float* p_fcpi_w = (const float*)d_in[27];
  const float* p_fcpi_b = (const float*)d_in[28];
  const float* inw = (const float*)d_in[29];
  const float* outw = (const float*)d_in[30];
  const float* outb = (const float*)d_in[31];

  // ws layout (bf16 elems) — round-10 proven layout, all buffers distinct.
  ushort_t* ws = (ushort_t*)d_ws;
  ushort_t* qbuf = ws;                  // [0, 4.19M)
  ushort_t* attn = ws + 4194304l;       // [4.19M, 8.39M)
  ushort_t* x1c  = ws + 8388608l;       // [8.39M, 16.78M)  chunk x1
  ushort_t* kvc  = ws + 16777216l;      // [16.78M, 33.55M) chunk kv
  ushort_t* wcv  = ws + 33554432l;      // converted weights (622,592)
  ushort_t* wbq = wcv;                  // whh_q bf16
  ushort_t* wbp = wcv + 196608l;        // whh_p bf16
  ushort_t* wf1 = wcv + 393216l;        // q_fc1_w bf16
  ushort_t* win = wcv + 425984l;        // q_attn_in_w bf16
  ushort_t* x2b = ws + 35651584l;       // distinct
  ushort_t* x3q = ws + 39845888l;
  ushort_t* x1p = ws + 44040192l;
  ushort_t* x3p = ws + 48234496l;
  ushort_t* giq = ws + 52428800l;       // 12,582,912
  ushort_t* gip = ws + 65011712l;       // 12,582,912 (end 77,594,624)

  float* out = (float*)d_out;
  float* o_q = out;
  float* o_pi = out + 1048576l;
  float* o_piA = out + 2097152l;
  float* o_hq = out + 3145728l;
  float* o_hp = out + 7340032l;

  const int nc = 4, CB = 512;
  const long MR = (long)CB * 64;  // 32768 rows per chunk
  const void* NUL = nullptr;

  // 0) pre-convert hot weights to bf16
  conv_k<<<608, 256, 0, stream>>>(q_whh, p_whh, q_fc1_w, inw, wcv);

  // 1) attention path, chunked so kv stays L3-resident (round-8 configs)
  for (int c = 0; c < nc; c++) {
    gemm_k<128, 0, 0, 1, 1, 0, 0, 0, 1><<<dim3(256, 2), 256, 0, stream>>>(
        entities + (long)c * MR * 128, wf1, q_fc1_b, em, x1c, nullptr, 0,
        (int)MR, 256, 128, NUL, NUL, nullptr, nullptr);
    gemm_k<128, 0, 0, 0, 0, 0, 0, 1, 0><<<dim3(256, 6), 256, 0, stream>>>(
        x1c, win, nullptr, em, kvc, qbuf, (long)c * MR, (int)MR, 768, 256,
        NUL, NUL, nullptr, nullptr);
    attn2_k<<<CB, 512, 0, stream>>>(kvc, qbuf, obs, attn, c * CB);
  }
  // 2) x2 = mask0(attn @ outw^T + outb)
  gemm_k<128, 2, 0, 0, 0, 1, 0, 0, 1><<<dim3(128, 2), 256, 0, stream>>>(
      attn, outw, outb, em, x2b, nullptr, 0, 16384, 256, 256,
      NUL, NUL, nullptr, nullptr);
  // 3) x1p = relu(ent[:, :8] @ fc1^T + b)
  gemm_k<128, 0, 1, 1, 1, 1, 0, 0, 1><<<dim3(128, 2), 256, 0, stream>>>(
      entities, p_fc1_w, p_fc1_b, em, x1p, nullptr, 0, 16384, 256, 128,
      NUL, NUL, nullptr, nullptr);
  // 4) z-batched x3: {x3q = relu(x2@q_fc2)} | {x3p = relu(x1p@p_fc2)}
  gemm_k<128, 0, 0, 1, 0, 1, 0, 0, 1><<<dim3(128, 2, 2), 256, 0, stream>>>(
      x2b, q_fc2_w, q_fc2_b, em, x3q, nullptr, 0, 16384, 256, 256,
      x1p, p_fc2_w, p_fc2_b, x3p);
  // 5) z-batched gi: {giq = x3q@q_wih + bih} | {gip = x3p@p_wih + bih}
  gemm_k<128, 0, 0, 0, 0, 1, 0, 0, 1><<<dim3(128, 6, 2), 256, 0, stream>>>(
      x3q, q_wih, q_bih, em, giq, nullptr, 0, 16384, 768, 256,
      x3p, p_wih, p_bih, gip);
  // 6) GRU scan v7 (gru4 + deferred hs store)
  gru7_k<<<32, 1024, 0, stream>>>(giq, gip, wbq, wbp, q_bhh, p_bhh, hidq, hidp,
                                  o_hq, o_hp);
  // 7) heads: o_q, then z-batched {pi from h_q} | {pi_avg from h_pi}
  gemm_k<64, 2, 0, 0, 1, 1, 1, 0, 1><<<dim3(128, 1), 256, 0, stream>>>(
      o_hq, q_fcq_w, q_fcq_b, em, o_q, nullptr, 0, 16384, 64, 256,
      NUL, NUL, nullptr, nullptr);
  gemm_k<64, 3, 0, 0, 1, 1, 1, 0, 1><<<dim3(128, 1, 2), 256, 0, stream>>>(
      o_hq, q_fcpi_w, q_fcpi_b, em, o_pi, nullptr, 0, 16384, 64, 256,
      o_hp, p_fcpi_w, p_fcpi_b, o_piA);
}